// Round 3
// baseline (227.838 us; speedup 1.0000x reference)
//
#include <hip/hip_runtime.h>
#include <hip/hip_bf16.h>

// Problem constants (reference: N=16384, C=2048, F=512; fp32 in/out).
constexpr int N_ROWS = 16384;
constexpr int C_CLS  = 2048;
constexpr int F_DIM  = 512;

typedef __bf16 bf16x8 __attribute__((ext_vector_type(8)));
typedef float  f32x16 __attribute__((ext_vector_type(16)));

// ---------------------------------------------------------------------------
// Fused pre-pass for BOTH inputs: fp32 -> bf16 + exact fp32 row sum-of-squares.
// Blocks [0, N) handle x rows; blocks [N, N+C) handle means rows.
// ---------------------------------------------------------------------------
__global__ __launch_bounds__(256) void prep_rows(
    const float* __restrict__ x,
    const float* __restrict__ means,
    __hip_bfloat162* __restrict__ xb,
    __hip_bfloat162* __restrict__ mb,
    float* __restrict__ xsq,
    float* __restrict__ msq)
{
    int row = blockIdx.x;
    const float* src;
    __hip_bfloat162* dst;
    float* sq;
    if (row < N_ROWS) { src = x; dst = xb; sq = xsq; }
    else { row -= N_ROWS; src = means; dst = mb; sq = msq; }

    const int tid = threadIdx.x;
    const float2 v = ((const float2*)(src + (size_t)row * F_DIM))[tid];

    __hip_bfloat162 p;
    p.x = __float2bfloat16(v.x);
    p.y = __float2bfloat16(v.y);
    dst[(size_t)row * (F_DIM / 2) + tid] = p;

    float ss = v.x * v.x + v.y * v.y;
    #pragma unroll
    for (int off = 32; off > 0; off >>= 1) ss += __shfl_down(ss, off);

    __shared__ float red[4];
    if ((tid & 63) == 0) red[tid >> 6] = ss;
    __syncthreads();
    if (tid == 0) sq[row] = red[0] + red[1] + red[2] + red[3];
}

// ---------------------------------------------------------------------------
// bf16 MFMA GEMM-BT with fused NCM epilogue — "flatmm-lite" + async pipeline.
//   * A (x rows) staged via global_load_lds into DOUBLE-buffered LDS, copies
//     for tile kt+1 issued right after the barrier for tile kt -> the vmcnt(0)
//     drain at the next barrier finds them already complete (1 barrier / kt).
//   * B (means rows, 2 MB, L2-resident) is NOT staged: each lane loads its
//     16-B MFMA B-fragment directly from global. B-frag layout for
//     v_mfma_f32_32x32x16_bf16 is B[k][n], n=lane&31, k=(lane>>5)*8+j --
//     i.e. 8 consecutive f of one means row: a single dwordx4 gather.
//   * XOR chunk swizzle on sA keeps ds_read_b128 conflict-free.
// ---------------------------------------------------------------------------
__device__ __forceinline__ void async_copy16(const __hip_bfloat16* g,
                                             __hip_bfloat16* l)
{
    __builtin_amdgcn_global_load_lds(
        (const __attribute__((address_space(1))) unsigned int*)g,
        (__attribute__((address_space(3))) unsigned int*)l,
        16, 0, 0);
}

__global__ __launch_bounds__(256) void ncm_gemm(
    const __hip_bfloat16* __restrict__ xb,   // [N, F] bf16
    const __hip_bfloat16* __restrict__ mb,   // [C, F] bf16
    const float* __restrict__ xsq,           // [N]
    const float* __restrict__ msq,           // [C]
    float* __restrict__ out)                 // [N, C] fp32
{
    constexpr int BM = 128, BK = 64, NKT = F_DIM / BK;   // 8 k-tiles

    __shared__ alignas(16) __hip_bfloat16 sA[2][BM * BK];  // 2 x 16 KB

    const int tid  = threadIdx.x;
    const int wave = tid >> 6;        // 0..3
    const int lane = tid & 63;
    const int wm   = wave >> 1;       // wave row (2x2)
    const int wn   = wave & 1;        // wave col

    const int row0 = blockIdx.y * BM; // over N (x rows)
    const int col0 = blockIdx.x * 128;// over C (means rows)

    // ---- A staging (swizzled): lane l -> row base+(l>>3), chunk (l&7)^(l>>3)
    const int srow   = lane >> 3;
    const int schunk = (lane & 7) ^ srow;
    const __hip_bfloat16* gA =
        xb + (size_t)(row0 + wave * 32 + srow) * F_DIM + schunk * 8;

    // ---- B direct-gather base: row = col0 + wn*64 + nt*32 + (lane&31),
    //      column = kt*64 + s*16 + (lane>>5)*8
    const int lrow  = lane & 31;
    const int khalf = lane >> 5;
    const __hip_bfloat16* gB =
        mb + (size_t)(col0 + wn * 64 + lrow) * F_DIM + khalf * 8;

    f32x16 acc[2][2] = {};

    // prologue: stage A tile 0 into buffer 0
    #pragma unroll
    for (int i = 0; i < 4; ++i)
        async_copy16(gA + (size_t)i * 8 * F_DIM,
                     &sA[0][(wave * 32 + i * 8) * BK]);

    for (int kt = 0; kt < NKT; ++kt) {
        const int p = kt & 1;
        __syncthreads();   // copies(kt) were issued a full phase ago -> cheap

        if (kt + 1 < NKT) {      // async prefetch A tile kt+1 into other buf
            const int k0n = (kt + 1) * BK;
            #pragma unroll
            for (int i = 0; i < 4; ++i)
                async_copy16(gA + (size_t)i * 8 * F_DIM + k0n,
                             &sA[1 - p][(wave * 32 + i * 8) * BK]);
        }

        // B fragments for this kt: 8 x dwordx4 gathers from L2-resident means
        bf16x8 bfr[4][2];
        #pragma unroll
        for (int s = 0; s < 4; ++s)
            #pragma unroll
            for (int nt = 0; nt < 2; ++nt)
                bfr[s][nt] = *(const bf16x8*)
                    (gB + (size_t)nt * 32 * F_DIM + kt * BK + s * 16);

        #pragma unroll
        for (int s = 0; s < 4; ++s) {
            // stored slot = chunk^(row&7); row&7 == lane&7 for the A read
            const int pos = ((2 * s + khalf) ^ (lane & 7)) * 8;
            bf16x8 af[2];
            #pragma unroll
            for (int mt = 0; mt < 2; ++mt)
                af[mt] = *(const bf16x8*)
                    &sA[p][(wm * 64 + mt * 32 + lrow) * BK + pos];
            #pragma unroll
            for (int mt = 0; mt < 2; ++mt)
                #pragma unroll
                for (int nt = 0; nt < 2; ++nt)
                    acc[mt][nt] = __builtin_amdgcn_mfma_f32_32x32x16_bf16(
                        af[mt], bfr[s][nt], acc[mt][nt], 0, 0, 0);
        }
    }

    // ---- epilogue: 32x32 C/D layout col=lane&31, row=(r&3)+8*(r>>2)+4*khalf
    #pragma unroll
    for (int mt = 0; mt < 2; ++mt) {
        const int rbase = row0 + wm * 64 + mt * 32 + 4 * khalf;
        float xs[16];
        #pragma unroll
        for (int r = 0; r < 16; ++r)
            xs[r] = xsq[rbase + (r & 3) + 8 * (r >> 2)];
        #pragma unroll
        for (int nt = 0; nt < 2; ++nt) {
            const int col = col0 + wn * 64 + nt * 32 + lrow;
            const float ms = msq[col];
            #pragma unroll
            for (int r = 0; r < 16; ++r) {
                const int row = rbase + (r & 3) + 8 * (r >> 2);
                const float d2 =
                    fmaxf(xs[r] + ms - 2.0f * acc[mt][nt][r], 0.0f);
                out[(size_t)row * C_CLS + col] = -sqrtf(d2);
            }
        }
    }
}

// ---------------------------------------------------------------------------
extern "C" void kernel_launch(void* const* d_in, const int* in_sizes, int n_in,
                              void* d_out, int out_size, void* d_ws,
                              size_t ws_size, hipStream_t stream)
{
    const float* x     = (const float*)d_in[0];   // [N, F]
    const float* means = (const float*)d_in[1];   // [C, F]
    float* out = (float*)d_out;                   // [N, C]

    char* ws = (char*)d_ws;
    __hip_bfloat16* xb = (__hip_bfloat16*)ws;                         // 16 MB
    __hip_bfloat16* mb = (__hip_bfloat16*)(ws + (size_t)N_ROWS * F_DIM * 2);
    float* xsq = (float*)(ws + (size_t)(N_ROWS + C_CLS) * F_DIM * 2);
    float* msq = xsq + N_ROWS;

    prep_rows<<<N_ROWS + C_CLS, 256, 0, stream>>>(
        x, means, (__hip_bfloat162*)xb, (__hip_bfloat162*)mb, xsq, msq);

    dim3 grid(C_CLS / 128, N_ROWS / 128);
    ncm_gemm<<<grid, 256, 0, stream>>>(xb, mb, xsq, msq, out);
}

// Round 4
// 209.218 us; speedup vs baseline: 1.0890x; 1.0890x over previous
//
#include <hip/hip_runtime.h>
#include <hip/hip_bf16.h>

// Problem constants (reference: N=16384, C=2048, F=512; fp32 in/out).
constexpr int N_ROWS = 16384;
constexpr int C_CLS  = 2048;
constexpr int F_DIM  = 512;

typedef __bf16 bf16x8 __attribute__((ext_vector_type(8)));
typedef float  f32x16 __attribute__((ext_vector_type(16)));

// ---------------------------------------------------------------------------
// Fused pre-pass for BOTH inputs: fp32 -> bf16 + exact fp32 row sum-of-squares.
// Blocks [0, N) handle x rows; blocks [N, N+C) handle means rows.
// ---------------------------------------------------------------------------
__global__ __launch_bounds__(256) void prep_rows(
    const float* __restrict__ x,
    const float* __restrict__ means,
    __hip_bfloat162* __restrict__ xb,
    __hip_bfloat162* __restrict__ mb,
    float* __restrict__ xsq,
    float* __restrict__ msq)
{
    int row = blockIdx.x;
    const float* src;
    __hip_bfloat162* dst;
    float* sq;
    if (row < N_ROWS) { src = x; dst = xb; sq = xsq; }
    else { row -= N_ROWS; src = means; dst = mb; sq = msq; }

    const int tid = threadIdx.x;
    const float2 v = ((const float2*)(src + (size_t)row * F_DIM))[tid];

    __hip_bfloat162 p;
    p.x = __float2bfloat16(v.x);
    p.y = __float2bfloat16(v.y);
    dst[(size_t)row * (F_DIM / 2) + tid] = p;

    float ss = v.x * v.x + v.y * v.y;
    #pragma unroll
    for (int off = 32; off > 0; off >>= 1) ss += __shfl_down(ss, off);

    __shared__ float red[4];
    if ((tid & 63) == 0) red[tid >> 6] = ss;
    __syncthreads();
    if (tid == 0) sq[row] = red[0] + red[1] + red[2] + red[3];
}

// ---------------------------------------------------------------------------
// bf16 MFMA GEMM-BT with fused NCM epilogue — single-barrier async pipeline.
// Both A and B staged via global_load_lds into DOUBLE-buffered LDS; the 8
// copies for tile kt+1 are issued immediately after the barrier for tile kt,
// so the vmcnt drain at the NEXT barrier finds them long complete (the
// CDNA analog of cp.async.wait_group pipelining; one barrier per k-tile).
// 128x128 block tile, BK=64, 4 waves 2x2, wave tile 64x64 = 2x2 of
// v_mfma_f32_32x32x16_bf16. XOR chunk swizzle on LDS (4-way residual
// conflict on the 32-row read pattern, measured non-binding).
// ---------------------------------------------------------------------------
__device__ __forceinline__ void async_copy16(const __hip_bfloat16* g,
                                             __hip_bfloat16* l)
{
    __builtin_amdgcn_global_load_lds(
        (const __attribute__((address_space(1))) unsigned int*)g,
        (__attribute__((address_space(3))) unsigned int*)l,
        16, 0, 0);
}

__global__ __launch_bounds__(256) void ncm_gemm(
    const __hip_bfloat16* __restrict__ xb,   // [N, F] bf16
    const __hip_bfloat16* __restrict__ mb,   // [C, F] bf16
    const float* __restrict__ xsq,           // [N]
    const float* __restrict__ msq,           // [C]
    float* __restrict__ out)                 // [N, C] fp32
{
    constexpr int BM = 128, BK = 64, NKT = F_DIM / BK;   // 8 k-tiles

    __shared__ alignas(16) __hip_bfloat16 sA[2][BM * BK];  // 2 x 16 KB
    __shared__ alignas(16) __hip_bfloat16 sB[2][BM * BK];  // 2 x 16 KB

    const int tid  = threadIdx.x;
    const int wave = tid >> 6;        // 0..3
    const int lane = tid & 63;
    const int wm   = wave >> 1;       // wave row (2x2)
    const int wn   = wave & 1;        // wave col

    const int row0 = blockIdx.y * BM; // over N (x rows)
    const int col0 = blockIdx.x * 128;// over C (means rows)

    // ---- staging addressing: lane l -> row base+(l>>3), chunk (l&7)^(l>>3),
    //      stored at slot l&7  =>  chunk c of row r lands at slot c^(r&7).
    const int srow   = lane >> 3;
    const int schunk = (lane & 7) ^ srow;
    const __hip_bfloat16* gA =
        xb + (size_t)(row0 + wave * 32 + srow) * F_DIM + schunk * 8;
    const __hip_bfloat16* gB =
        mb + (size_t)(col0 + wave * 32 + srow) * F_DIM + schunk * 8;

    f32x16 acc[2][2] = {};

    const int lrow  = lane & 31;   // A row (m) / B col (n) within 32-tile
    const int khalf = lane >> 5;   // which 8-wide half of K=16

    // prologue: stage tile 0 into buffer 0
    #pragma unroll
    for (int i = 0; i < 4; ++i) {
        async_copy16(gA + (size_t)i * 8 * F_DIM,
                     &sA[0][(wave * 32 + i * 8) * BK]);
        async_copy16(gB + (size_t)i * 8 * F_DIM,
                     &sB[0][(wave * 32 + i * 8) * BK]);
    }

    for (int kt = 0; kt < NKT; ++kt) {
        const int p = kt & 1;
        __syncthreads();   // copies(kt) were issued a full phase ago -> cheap

        if (kt + 1 < NKT) {      // async prefetch tile kt+1 into other buffer
            const int k0n = (kt + 1) * BK;
            #pragma unroll
            for (int i = 0; i < 4; ++i) {
                async_copy16(gA + (size_t)i * 8 * F_DIM + k0n,
                             &sA[1 - p][(wave * 32 + i * 8) * BK]);
                async_copy16(gB + (size_t)i * 8 * F_DIM + k0n,
                             &sB[1 - p][(wave * 32 + i * 8) * BK]);
            }
        }

        #pragma unroll
        for (int s = 0; s < 4; ++s) {           // 4 k-steps of 16 within BK=64
            // lane needs chunk 2s+khalf of its row; slot = chunk^(row&7),
            // row&7 == lane&7 for both operands.
            const int pos = ((2 * s + khalf) ^ (lane & 7)) * 8;
            bf16x8 af[2], bfr[2];
            #pragma unroll
            for (int mt = 0; mt < 2; ++mt)
                af[mt] = *(const bf16x8*)
                    &sA[p][(wm * 64 + mt * 32 + lrow) * BK + pos];
            #pragma unroll
            for (int nt = 0; nt < 2; ++nt)
                bfr[nt] = *(const bf16x8*)
                    &sB[p][(wn * 64 + nt * 32 + lrow) * BK + pos];
            #pragma unroll
            for (int mt = 0; mt < 2; ++mt)
                #pragma unroll
                for (int nt = 0; nt < 2; ++nt)
                    acc[mt][nt] = __builtin_amdgcn_mfma_f32_32x32x16_bf16(
                        af[mt], bfr[nt], acc[mt][nt], 0, 0, 0);
        }
    }

    // ---- epilogue: 32x32 C/D layout col=lane&31, row=(r&3)+8*(r>>2)+4*khalf
    #pragma unroll
    for (int mt = 0; mt < 2; ++mt) {
        const int rbase = row0 + wm * 64 + mt * 32 + 4 * khalf;
        float xs[16];
        #pragma unroll
        for (int r = 0; r < 16; ++r)
            xs[r] = xsq[rbase + (r & 3) + 8 * (r >> 2)];
        #pragma unroll
        for (int nt = 0; nt < 2; ++nt) {
            const int col = col0 + wn * 64 + nt * 32 + lrow;
            const float ms = msq[col];
            #pragma unroll
            for (int r = 0; r < 16; ++r) {
                const int row = rbase + (r & 3) + 8 * (r >> 2);
                const float d2 =
                    fmaxf(xs[r] + ms - 2.0f * acc[mt][nt][r], 0.0f);
                out[(size_t)row * C_CLS + col] = -sqrtf(d2);
            }
        }
    }
}

// ---------------------------------------------------------------------------
extern "C" void kernel_launch(void* const* d_in, const int* in_sizes, int n_in,
                              void* d_out, int out_size, void* d_ws,
                              size_t ws_size, hipStream_t stream)
{
    const float* x     = (const float*)d_in[0];   // [N, F]
    const float* means = (const float*)d_in[1];   // [C, F]
    float* out = (float*)d_out;                   // [N, C]

    char* ws = (char*)d_ws;
    __hip_bfloat16* xb = (__hip_bfloat16*)ws;                         // 16 MB
    __hip_bfloat16* mb = (__hip_bfloat16*)(ws + (size_t)N_ROWS * F_DIM * 2);
    float* xsq = (float*)(ws + (size_t)(N_ROWS + C_CLS) * F_DIM * 2);
    float* msq = xsq + N_ROWS;

    prep_rows<<<N_ROWS + C_CLS, 256, 0, stream>>>(
        x, means, (__hip_bfloat162*)xb, (__hip_bfloat162*)mb, xsq, msq);

    dim3 grid(C_CLS / 128, N_ROWS / 128);
    ncm_gemm<<<grid, 256, 0, stream>>>(xb, mb, xsq, msq, out);
}